// Round 1
// baseline (163.457 us; speedup 1.0000x reference)
//
#include <hip/hip_runtime.h>

// GroupedEmbeddingBag: T=8 tables, V=100000, D=128, B=4096 bags, L=204800 ids/table.
// out[b, t*128 + d] = sum_{i in bag(t,b)} weights[t, values[t,i], d]
//
// Strategy: one 64-lane wave per (t, b). Lane owns float2 of the 128-float row
// (64 * 8B = 512B coalesced load per id). 4-deep unroll for MLP.

#define T_TABLES 8
#define V_VOCAB  100000
#define D_DIM    128
#define B_BAGS   4096
#define L_IDS    204800   // B * AVG(50)

__global__ __launch_bounds__(256) void geb_pool_kernel(
    const int*   __restrict__ values,   // [T, L]
    const int*   __restrict__ offsets,  // [T, B+1]
    const float* __restrict__ weights,  // [T, V, D]
    float*       __restrict__ out)      // [B, T*D]
{
    const int gtid = blockIdx.x * blockDim.x + threadIdx.x;
    const int wave = gtid >> 6;
    const int lane = threadIdx.x & 63;
    const int t = wave / B_BAGS;
    const int b = wave - t * B_BAGS;
    if (t >= T_TABLES) return;

    const int* offs = offsets + t * (B_BAGS + 1);
    const int start = offs[b];
    const int end   = offs[b + 1];

    const int*   vals = values + (size_t)t * L_IDS;
    const float* Wt   = weights + (size_t)t * V_VOCAB * D_DIM;

    float2 a0 = make_float2(0.f, 0.f);
    float2 a1 = make_float2(0.f, 0.f);
    float2 a2 = make_float2(0.f, 0.f);
    float2 a3 = make_float2(0.f, 0.f);

    int i = start;
    // 4-deep unroll: 4 independent 512B gathers in flight per wave
    for (; i + 3 < end; i += 4) {
        const int v0 = vals[i + 0];
        const int v1 = vals[i + 1];
        const int v2 = vals[i + 2];
        const int v3 = vals[i + 3];
        const float2 w0 = ((const float2*)(Wt + (size_t)v0 * D_DIM))[lane];
        const float2 w1 = ((const float2*)(Wt + (size_t)v1 * D_DIM))[lane];
        const float2 w2 = ((const float2*)(Wt + (size_t)v2 * D_DIM))[lane];
        const float2 w3 = ((const float2*)(Wt + (size_t)v3 * D_DIM))[lane];
        a0.x += w0.x; a0.y += w0.y;
        a1.x += w1.x; a1.y += w1.y;
        a2.x += w2.x; a2.y += w2.y;
        a3.x += w3.x; a3.y += w3.y;
    }
    for (; i < end; ++i) {
        const int v = vals[i];
        const float2 w = ((const float2*)(Wt + (size_t)v * D_DIM))[lane];
        a0.x += w.x; a0.y += w.y;
    }

    const float2 acc = make_float2(a0.x + a1.x + a2.x + a3.x,
                                   a0.y + a1.y + a2.y + a3.y);

    // out[b][t*D + 2*lane .. +1]
    float2* o = (float2*)(out + (size_t)b * (T_TABLES * D_DIM) + (size_t)t * D_DIM);
    o[lane] = acc;
}

extern "C" void kernel_launch(void* const* d_in, const int* in_sizes, int n_in,
                              void* d_out, int out_size, void* d_ws, size_t ws_size,
                              hipStream_t stream) {
    const int*   values  = (const int*)d_in[0];
    const int*   offsets = (const int*)d_in[1];
    const float* weights = (const float*)d_in[2];
    float*       out     = (float*)d_out;

    const int total_waves     = T_TABLES * B_BAGS;      // 32768
    const int threads         = 256;
    const int waves_per_block = threads / 64;           // 4
    const int blocks          = total_waves / waves_per_block;  // 8192

    geb_pool_kernel<<<blocks, threads, 0, stream>>>(values, offsets, weights, out);
}

// Round 2
// 139.962 us; speedup vs baseline: 1.1679x; 1.1679x over previous
//
#include <hip/hip_runtime.h>

// GroupedEmbeddingBag: T=8 tables, V=100000, D=128, B=4096 bags, L=204800 ids/table.
// out[b, t*128 + d] = sum_{i in bag(t,b)} weights[t, values[t,i], d]
//
// R1 strategy: one 64-lane wave per (t, b). Lane loads float4 (16B), so one
// wave-load covers TWO rows: lanes 0-31 -> id i, lanes 32-63 -> id i+1.
// Unroll 8 ids/iter = 4 x dwordx4 loads = 4KB in flight per wave-iteration
// (2x R0), half the trip count. Cross-half reduce via __shfl_xor(32).

#define T_TABLES 8
#define V_VOCAB  100000
#define D_DIM    128
#define B_BAGS   4096
#define L_IDS    204800   // B * AVG(50)

__global__ __launch_bounds__(256) void geb_pool_kernel(
    const int*   __restrict__ values,   // [T, L]
    const int*   __restrict__ offsets,  // [T, B+1]
    const float* __restrict__ weights,  // [T, V, D]
    float*       __restrict__ out)      // [B, T*D]
{
    const int gtid = blockIdx.x * blockDim.x + threadIdx.x;
    const int wave = gtid >> 6;
    const int lane = threadIdx.x & 63;
    const int half = lane >> 5;   // 0: even ids, 1: odd ids
    const int dq   = lane & 31;   // float4 slot within the 128-float row
    const int t = wave / B_BAGS;
    const int b = wave - t * B_BAGS;
    if (t >= T_TABLES) return;

    const int* offs = offsets + t * (B_BAGS + 1);
    const int start = offs[b];
    const int end   = offs[b + 1];

    const int*   vals = values + (size_t)t * L_IDS;
    const float* Wt   = weights + (size_t)t * V_VOCAB * D_DIM;

    float4 a0 = make_float4(0.f, 0.f, 0.f, 0.f);
    float4 a1 = make_float4(0.f, 0.f, 0.f, 0.f);
    float4 a2 = make_float4(0.f, 0.f, 0.f, 0.f);
    float4 a3 = make_float4(0.f, 0.f, 0.f, 0.f);

    int i = start;
    // main: 8 ids per iteration, 4 paired dwordx4 gathers in flight
    for (; i + 8 <= end; i += 8) {
        const int va = vals[i + 0 + half];
        const int vb = vals[i + 2 + half];
        const int vc = vals[i + 4 + half];
        const int vd = vals[i + 6 + half];
        const float4 wa = ((const float4*)(Wt + (size_t)va * D_DIM))[dq];
        const float4 wb = ((const float4*)(Wt + (size_t)vb * D_DIM))[dq];
        const float4 wc = ((const float4*)(Wt + (size_t)vc * D_DIM))[dq];
        const float4 wd = ((const float4*)(Wt + (size_t)vd * D_DIM))[dq];
        a0.x += wa.x; a0.y += wa.y; a0.z += wa.z; a0.w += wa.w;
        a1.x += wb.x; a1.y += wb.y; a1.z += wb.z; a1.w += wb.w;
        a2.x += wc.x; a2.y += wc.y; a2.z += wc.z; a2.w += wc.w;
        a3.x += wd.x; a3.y += wd.y; a3.z += wd.z; a3.w += wd.w;
    }
    // tail pairs
    for (; i + 2 <= end; i += 2) {
        const int v = vals[i + half];
        const float4 w = ((const float4*)(Wt + (size_t)v * D_DIM))[dq];
        a0.x += w.x; a0.y += w.y; a0.z += w.z; a0.w += w.w;
    }
    // final odd id: only half 0 covers it (32 lanes x float4 = full row)
    if (i < end && half == 0) {
        const int v = vals[i];
        const float4 w = ((const float4*)(Wt + (size_t)v * D_DIM))[dq];
        a0.x += w.x; a0.y += w.y; a0.z += w.z; a0.w += w.w;
    }

    float4 acc = make_float4(a0.x + a1.x + a2.x + a3.x,
                             a0.y + a1.y + a2.y + a3.y,
                             a0.z + a1.z + a2.z + a3.z,
                             a0.w + a1.w + a2.w + a3.w);

    // combine the two half-wave partial sums (same dq slot, lane ^ 32)
    acc.x += __shfl_xor(acc.x, 32, 64);
    acc.y += __shfl_xor(acc.y, 32, 64);
    acc.z += __shfl_xor(acc.z, 32, 64);
    acc.w += __shfl_xor(acc.w, 32, 64);

    if (half == 0) {
        float4* o = (float4*)(out + (size_t)b * (T_TABLES * D_DIM) + (size_t)t * D_DIM);
        o[dq] = acc;
    }
}

extern "C" void kernel_launch(void* const* d_in, const int* in_sizes, int n_in,
                              void* d_out, int out_size, void* d_ws, size_t ws_size,
                              hipStream_t stream) {
    const int*   values  = (const int*)d_in[0];
    const int*   offsets = (const int*)d_in[1];
    const float* weights = (const float*)d_in[2];
    float*       out     = (float*)d_out;

    const int total_waves     = T_TABLES * B_BAGS;      // 32768
    const int threads         = 256;
    const int waves_per_block = threads / 64;           // 4
    const int blocks          = total_waves / waves_per_block;  // 8192

    geb_pool_kernel<<<blocks, threads, 0, stream>>>(values, offsets, weights, out);
}

// Round 3
// 136.460 us; speedup vs baseline: 1.1978x; 1.0257x over previous
//
#include <hip/hip_runtime.h>

// GroupedEmbeddingBag: T=8 tables, V=100000, D=128, B=4096 bags, L=204800 ids/table.
// out[b, t*128 + d] = sum_{i in bag(t,b)} weights[t, values[t,i], d]
//
// R2 strategy: one 64-lane wave per (t, b).
//  - Load up to 64 bag ids in ONE vector load (lane l -> vals[base+l]).
//  - Broadcast each id to SGPR via readlane (no memory latency on the id path).
//  - Gather: uniform SGPR row base + lane*8B offset -> one global_load_dwordx2
//    per id = exactly 512B, perfectly coalesced, scalar address math.
//  - 8 loads in flight per inner iteration (4KB/wave), 4 accumulator chains.

#define T_TABLES 8
#define V_VOCAB  100000
#define D_DIM    128
#define B_BAGS   4096
#define L_IDS    204800   // B * AVG(50)

__global__ __launch_bounds__(256) void geb_pool_kernel(
    const int*   __restrict__ values,   // [T, L]
    const int*   __restrict__ offsets,  // [T, B+1]
    const float* __restrict__ weights,  // [T, V, D]
    float*       __restrict__ out)      // [B, T*D]
{
    const int gtid = blockIdx.x * blockDim.x + threadIdx.x;
    const int wave = gtid >> 6;
    const int lane = threadIdx.x & 63;
    const int t = wave / B_BAGS;
    const int b = wave - t * B_BAGS;
    if (t >= T_TABLES) return;

    const int* offs = offsets + t * (B_BAGS + 1);
    const int start = offs[b];
    const int end   = offs[b + 1];

    const int*   vals = values + (size_t)t * L_IDS;
    const float* Wt   = weights + (size_t)t * V_VOCAB * D_DIM;

    float2 a0 = make_float2(0.f, 0.f);
    float2 a1 = make_float2(0.f, 0.f);
    float2 a2 = make_float2(0.f, 0.f);
    float2 a3 = make_float2(0.f, 0.f);

    for (int base = start; base < end; base += 64) {
        int nb = end - base;
        if (nb > 64) nb = 64;
        // one coalesced load fetches this chunk's ids into lane-registers
        int myid = 0;
        if (base + lane < end) myid = vals[base + lane];

        int j = 0;
        for (; j + 8 <= nb; j += 8) {
            const int v0 = __builtin_amdgcn_readlane(myid, j + 0);
            const int v1 = __builtin_amdgcn_readlane(myid, j + 1);
            const int v2 = __builtin_amdgcn_readlane(myid, j + 2);
            const int v3 = __builtin_amdgcn_readlane(myid, j + 3);
            const int v4 = __builtin_amdgcn_readlane(myid, j + 4);
            const int v5 = __builtin_amdgcn_readlane(myid, j + 5);
            const int v6 = __builtin_amdgcn_readlane(myid, j + 6);
            const int v7 = __builtin_amdgcn_readlane(myid, j + 7);
            const float2 w0 = *(const float2*)(Wt + (size_t)v0 * D_DIM + 2 * lane);
            const float2 w1 = *(const float2*)(Wt + (size_t)v1 * D_DIM + 2 * lane);
            const float2 w2 = *(const float2*)(Wt + (size_t)v2 * D_DIM + 2 * lane);
            const float2 w3 = *(const float2*)(Wt + (size_t)v3 * D_DIM + 2 * lane);
            const float2 w4 = *(const float2*)(Wt + (size_t)v4 * D_DIM + 2 * lane);
            const float2 w5 = *(const float2*)(Wt + (size_t)v5 * D_DIM + 2 * lane);
            const float2 w6 = *(const float2*)(Wt + (size_t)v6 * D_DIM + 2 * lane);
            const float2 w7 = *(const float2*)(Wt + (size_t)v7 * D_DIM + 2 * lane);
            a0.x += w0.x; a0.y += w0.y;  a1.x += w1.x; a1.y += w1.y;
            a2.x += w2.x; a2.y += w2.y;  a3.x += w3.x; a3.y += w3.y;
            a0.x += w4.x; a0.y += w4.y;  a1.x += w5.x; a1.y += w5.y;
            a2.x += w6.x; a2.y += w6.y;  a3.x += w7.x; a3.y += w7.y;
        }
        for (; j < nb; ++j) {
            const int v = __builtin_amdgcn_readlane(myid, j);
            const float2 w = *(const float2*)(Wt + (size_t)v * D_DIM + 2 * lane);
            a0.x += w.x; a0.y += w.y;
        }
    }

    const float2 acc = make_float2(a0.x + a1.x + a2.x + a3.x,
                                   a0.y + a1.y + a2.y + a3.y);

    // lane owns out[b][t*128 + 2*lane .. +1]
    float2* o = (float2*)(out + (size_t)b * (T_TABLES * D_DIM) + (size_t)t * D_DIM);
    o[lane] = acc;
}

extern "C" void kernel_launch(void* const* d_in, const int* in_sizes, int n_in,
                              void* d_out, int out_size, void* d_ws, size_t ws_size,
                              hipStream_t stream) {
    const int*   values  = (const int*)d_in[0];
    const int*   offsets = (const int*)d_in[1];
    const float* weights = (const float*)d_in[2];
    float*       out     = (float*)d_out;

    const int total_waves     = T_TABLES * B_BAGS;      // 32768
    const int threads         = 256;
    const int waves_per_block = threads / 64;           // 4
    const int blocks          = total_waves / waves_per_block;  // 8192

    geb_pool_kernel<<<blocks, threads, 0, stream>>>(values, offsets, weights, out);
}